// Round 4
// baseline (501.007 us; speedup 1.0000x reference)
//
#include <hip/hip_runtime.h>

// AdditiveAttention on MI355X (gfx950)
// B=64, S=2048, D=512, U=512. All inputs fp32; output fp32 (B,D).
//
// R4: scores_k K-loop moved to 32x32x16 MFMA (wave = 2mt x 2nt, acc 64 AGPR)
// so per-k-step B is only 8 VGPR => explicit depth-4 B prefetch ring (32 VGPR)
// + per-wave k-step stagger to decorrelate load bursts. B-frag layout v2
// (32x32 fragment order). Traffic unchanged vs R3; latency exposure attacked.

typedef __attribute__((ext_vector_type(8))) short bf16x8;
typedef __attribute__((ext_vector_type(16))) float f32x16;

#if __has_builtin(__builtin_amdgcn_exp2f)
__device__ __forceinline__ float fast_exp2(float x) { return __builtin_amdgcn_exp2f(x); }
#else
__device__ __forceinline__ float fast_exp2(float x) { return exp2f(x); }
#endif
#if __has_builtin(__builtin_amdgcn_rcpf)
__device__ __forceinline__ float fast_rcp(float x) { return __builtin_amdgcn_rcpf(x); }
#else
__device__ __forceinline__ float fast_rcp(float x) { return 1.0f / x; }
#endif

__device__ __forceinline__ unsigned short f2bf(float f) {
  unsigned int u = __float_as_uint(f);
  u += 0x7fffu + ((u >> 16) & 1u);
  return (unsigned short)(u >> 16);
}

// ---------------- k1: Q = query @ W1  (64x2 blocks x 256 thr) ---------------
__global__ void qk(const float* __restrict__ query, const float* __restrict__ W1,
                   float* __restrict__ Q) {
  __shared__ float qrow[512];
  const int b = blockIdx.x, half = blockIdx.y, t = threadIdx.x;
  qrow[t] = query[b * 512 + t];
  qrow[t + 256] = query[b * 512 + t + 256];
  __syncthreads();
  const int u = half * 256 + t;
  float acc = 0.f;
#pragma unroll 8
  for (int k = 0; k < 512; ++k) acc += qrow[k] * W1[(size_t)k * 512 + u];
  Q[b * 512 + u] = acc;
}

// ---------------- k2: Wtf = 32x32-fragment-ordered bf16(W2^T); zero out -----
// frag f = nt32*32 + ks (nt32 0..15, ks 0..31). Within frag, lane L holds
// n = nt32*32 + (L&31), k = ks*16 + (L>>5)*8 + j (j=0..7), at Wtf[f*512+L*8].
__global__ void wt_k(const float* __restrict__ W2, unsigned short* __restrict__ Wtf,
                     float* __restrict__ out0) {
  const int gid = blockIdx.x * 256 + threadIdx.x;  // 0..32767
  out0[gid] = 0.f;                                 // zero d_out for ctx atomics
  const int lane = gid & 63;
  const int frag = gid >> 6;
  const int ks = frag & 31, nt32 = frag >> 5;
  const int n = nt32 * 32 + (lane & 31);
  const int k0 = ks * 16 + (lane >> 5) * 8;
  unsigned int p[4];
#pragma unroll
  for (int jj = 0; jj < 4; ++jj) {
    const float a = W2[(size_t)(k0 + 2 * jj) * 512 + n];
    const float b = W2[(size_t)(k0 + 2 * jj + 1) * 512 + n];
    p[jj] = (unsigned int)f2bf(a) | ((unsigned int)f2bf(b) << 16);
  }
  *(uint4*)&Wtf[(size_t)gid * 8] = make_uint4(p[0], p[1], p[2], p[3]);
}

// ---------------- k3: fused scores ------------------------------------------
// Block: 64 rows x full U=512, K=512. 8 waves; wave w owns n-tiles32 {2w,2w+1}
// as 2mt x 2nt of 32x32x16 MFMA. A in LDS (bf16, xor-swizzled 16B chunks).
// B: depth-4 register prefetch ring from fragment-ordered Wtf (L2-resident).
// Per-wave k-stagger (+4w mod 32) decorrelates memory bursts across waves.
__global__ __launch_bounds__(512, 4) void scores_k(
    const float* __restrict__ values, const unsigned short* __restrict__ Wtf,
    const float* __restrict__ Q, const float* __restrict__ V1,
    float* __restrict__ scores) {
  __shared__ __align__(16) unsigned short Ab[64 * 512];  // [m][512k], swizzled
  __shared__ float sAcc[64];

  const int t = threadIdx.x;
  const int lane = t & 63;
  const int w = t >> 6;       // wave 0..7
  const int hi = lane >> 5;   // 0/1
  const int l31 = lane & 31;
  const int m0 = blockIdx.x * 64;
  const int b = m0 >> 11;  // /2048

  if (t < 64) sAcc[t] = 0.0f;

  // ---- stage A: 64 rows x 512 k, fp32 -> bf16, swizzled 16B chunks
  const float* Ag = values + (size_t)m0 * 512;
#pragma unroll
  for (int i = 0; i < 8; ++i) {
    const int c = i * 512 + t;  // chunk id: 64 rows x 64 chunks
    const int m = c >> 6;
    const int kc = c & 63;
    const float4* src = (const float4*)(Ag + (size_t)m * 512 + kc * 8);
    const float4 x = src[0], y = src[1];
    const unsigned int p0 = (unsigned int)f2bf(x.x) | ((unsigned int)f2bf(x.y) << 16);
    const unsigned int p1 = (unsigned int)f2bf(x.z) | ((unsigned int)f2bf(x.w) << 16);
    const unsigned int p2 = (unsigned int)f2bf(y.x) | ((unsigned int)f2bf(y.y) << 16);
    const unsigned int p3 = (unsigned int)f2bf(y.z) | ((unsigned int)f2bf(y.w) << 16);
    *(uint4*)&Ab[m * 512 + ((kc ^ (m & 7)) * 8)] = make_uint4(p0, p1, p2, p3);
  }
  __syncthreads();

  f32x16 acc[2][2];
#pragma unroll
  for (int mt = 0; mt < 2; ++mt)
#pragma unroll
    for (int nt = 0; nt < 2; ++nt)
#pragma unroll
      for (int r = 0; r < 16; ++r) acc[mt][nt][r] = 0.f;

  const int w4 = w * 4;  // k-step stagger
  // B bases: wave w -> frag blocks (w*2)*32 and (w*2+1)*32
  const unsigned short* Bg0 = Wtf + (size_t)(w * 2) * 32 * 512 + (size_t)lane * 8;
  const unsigned short* Bg1 = Bg0 + 32 * 512;
  const int sw = l31 & 7;  // A swizzle key (m&7 == l31&7)

  // depth-4 B prefetch ring
  bf16x8 Bb[4][2];
#pragma unroll
  for (int p = 0; p < 4; ++p) {
    const int ksx = (p + w4) & 31;
    Bb[p][0] = *(const bf16x8*)(Bg0 + (size_t)ksx * 512);
    Bb[p][1] = *(const bf16x8*)(Bg1 + (size_t)ksx * 512);
  }

#pragma unroll
  for (int ks = 0; ks < 32; ++ks) {
    const int pb = ks & 3;
    const int ksx = (ks + w4) & 31;
    const int kc = ksx * 2 + hi;  // A 16B-chunk index
    bf16x8 af[2];
#pragma unroll
    for (int mt = 0; mt < 2; ++mt) {
      const int m = mt * 32 + l31;
      af[mt] = *(const bf16x8*)&Ab[m * 512 + ((kc ^ sw) * 8)];
    }
#pragma unroll
    for (int mt = 0; mt < 2; ++mt)
#pragma unroll
      for (int nt = 0; nt < 2; ++nt)
        acc[mt][nt] = __builtin_amdgcn_mfma_f32_32x32x16_bf16(af[mt], Bb[pb][nt],
                                                              acc[mt][nt], 0, 0, 0);
    if (ks < 28) {
      const int ksn = ((ks + 4) + w4) & 31;
      Bb[pb][0] = *(const bf16x8*)(Bg0 + (size_t)ksn * 512);
      Bb[pb][1] = *(const bf16x8*)(Bg1 + (size_t)ksn * 512);
    }
  }

  // ---- epilogue: score[m] += tanh(acc + Q[b,n]) * V1[n] reduced over n
  // 32x32 C/D layout: col n = lane&31, row = (reg&3) + 8*(reg>>2) + 4*(lane>>5)
  float qv[2], v1v[2];
#pragma unroll
  for (int nt = 0; nt < 2; ++nt) {
    const int n = w * 64 + nt * 32 + l31;
    qv[nt] = Q[b * 512 + n];
    v1v[nt] = V1[n];
  }
#pragma unroll
  for (int mt = 0; mt < 2; ++mt) {
    float rsum[16];
#pragma unroll
    for (int reg = 0; reg < 16; ++reg) {
      float s = 0.f;
#pragma unroll
      for (int nt = 0; nt < 2; ++nt) {
        const float x = acc[mt][nt][reg] + qv[nt];
        const float e = fast_exp2(x * 2.8853900817779268f);  // e^{2x}
        const float th = 1.0f - 2.0f * fast_rcp(e + 1.0f);   // tanh(x)
        s += th * v1v[nt];
      }
      // reduce across the 32 columns (lane bits 0..4; rows uniform per half)
      s += __shfl_xor(s, 1);
      s += __shfl_xor(s, 2);
      s += __shfl_xor(s, 4);
      s += __shfl_xor(s, 8);
      s += __shfl_xor(s, 16);
      rsum[reg] = s;
    }
    if (l31 == 0) {
#pragma unroll
      for (int reg = 0; reg < 16; ++reg) {
        const int row = mt * 32 + (reg & 3) + 8 * (reg >> 2) + 4 * hi;
        atomicAdd(&sAcc[row], rsum[reg]);
      }
    }
  }
  __syncthreads();
  if (t < 64) scores[m0 + t] = sAcc[t];
}

// ---------------- k4: context with fused softmax ----------------------------
// grid 512: (b, s-chunk of 256); 512 thr. Each block recomputes softmax stats
// over its b's 2048 raw scores (8KB, trivial), then accumulates its 256-s
// chunk into out via atomicAdd (out zeroed by wt_k).
__global__ __launch_bounds__(512) void ctx_k(const float* __restrict__ values,
                                             const float* __restrict__ scores,
                                             float* __restrict__ out) {
  __shared__ float red[16];
  __shared__ float wsc[256];
  const int bid = blockIdx.x;
  const int b = bid >> 3, sc = bid & 7;
  const int t = threadIdx.x;
  const float* sb = scores + (size_t)b * 2048;
  const float v0 = sb[t], v1 = sb[t + 512], v2 = sb[t + 1024], v3 = sb[t + 1536];
  float mx = fmaxf(fmaxf(v0, v1), fmaxf(v2, v3));
#pragma unroll
  for (int o = 1; o < 64; o <<= 1) mx = fmaxf(mx, __shfl_xor(mx, o));
  if ((t & 63) == 0) red[t >> 6] = mx;
  __syncthreads();
  mx = fmaxf(fmaxf(fmaxf(red[0], red[1]), fmaxf(red[2], red[3])),
             fmaxf(fmaxf(red[4], red[5]), fmaxf(red[6], red[7])));
  const float L2E = 1.4426950408889634f;
  float sum = fast_exp2((v0 - mx) * L2E) + fast_exp2((v1 - mx) * L2E) +
              fast_exp2((v2 - mx) * L2E) + fast_exp2((v3 - mx) * L2E);
#pragma unroll
  for (int o = 1; o < 64; o <<= 1) sum += __shfl_xor(sum, o);
  if ((t & 63) == 0) red[8 + (t >> 6)] = sum;
  __syncthreads();
  sum = (red[8] + red[9]) + (red[10] + red[11]) + (red[12] + red[13]) +
        (red[14] + red[15]);
  const float inv = 1.0f / sum;
  if (t < 256) wsc[t] = fast_exp2((sb[sc * 256 + t] - mx) * L2E) * inv;
  __syncthreads();
  const float* vb = values + ((size_t)b * 2048 + sc * 256) * 512;
  float acc = 0.f;
#pragma unroll 8
  for (int s = 0; s < 256; ++s) acc += wsc[s] * vb[(size_t)s * 512 + t];
  atomicAdd(&out[b * 512 + t], acc);
}

extern "C" void kernel_launch(void* const* d_in, const int* in_sizes, int n_in,
                              void* d_out, int out_size, void* d_ws, size_t ws_size,
                              hipStream_t stream) {
  const float* query = (const float*)d_in[0];   // (64, 512)
  const float* values = (const float*)d_in[1];  // (64, 2048, 512)
  const float* W1 = (const float*)d_in[2];      // (512, 512)
  const float* W2 = (const float*)d_in[3];      // (512, 512)
  const float* V1 = (const float*)d_in[4];      // (512, 1)
  float* out = (float*)d_out;                   // (64, 512)

  char* ws = (char*)d_ws;
  float* Qp = (float*)ws;                                // 131072 B
  unsigned short* Wtp = (unsigned short*)(ws + 131072);  // 524288 B
  float* Sp = (float*)(ws + 131072 + 524288);            // 524288 B

  qk<<<dim3(64, 2), 256, 0, stream>>>(query, W1, Qp);
  wt_k<<<128, 256, 0, stream>>>(W2, Wtp, out);
  scores_k<<<2048, 512, 0, stream>>>(values, Wtp, Qp, V1, Sp);
  ctx_k<<<512, 512, 0, stream>>>(values, Sp, out);
}